// Round 1
// baseline (9768.101 us; speedup 1.0000x reference)
//
#include <hip/hip_runtime.h>

#define Bz 512
#define Tz 20
#define NOBJz 36
#define Dz 2048
#define EMBz 300
#define Ez 512
#define HMz 1024
#define HOz 256
#define KAM 1836   // HM + E + EMB   (mask step-GEMM K)
#define KAO 1580   // HO + 2E + EMB  (obj step-GEMM K)

__device__ __forceinline__ float sigf(float x) { return 1.f / (1.f + __expf(-x)); }

// ---- obj mask: one wave per (b, n) row, reduce |.| over D ----
__global__ void obj_mask_kernel(const float* __restrict__ obj_enc, float* __restrict__ mask) {
    int bn = blockIdx.x;            // b*NOBJ + n
    int lane = threadIdx.x;         // 64 threads = 1 wave
    const float* row = obj_enc + (size_t)bn * Dz;
    float s = 0.f;
    for (int d = lane; d < Dz; d += 64) s += fabsf(row[d]);
    for (int off = 32; off > 0; off >>= 1) s += __shfl_down(s, off);
    if (lane == 0) mask[bn] = (s > 0.f) ? 1.f : 0.f;
}

// ---- meanimfeats[b,d] = sum_n obj_enc[b,n,d]*mask[b,n] / max(sum_n mask, 1e-9) ----
__global__ void meanim_kernel(const float* __restrict__ obj_enc, const float* __restrict__ mask,
                              float* __restrict__ meanim) {
    int idx = blockIdx.x * 256 + threadIdx.x;
    if (idx >= Bz * Dz) return;
    int b = idx / Dz, d = idx - b * Dz;
    float s = 0.f, cnt = 0.f;
    for (int n = 0; n < NOBJz; ++n) {
        float m = mask[b * NOBJz + n];
        cnt += m;
        s += obj_enc[((size_t)b * NOBJz + n) * Dz + d] * m;
    }
    meanim[idx] = s / fmaxf(cnt, 1e-9f);
}

// ---- embedding gather: xemb[b,t,:] = emd_W[x[b,t],:] ----
__global__ void embed_kernel(const int* __restrict__ x, const float* __restrict__ emd,
                             float* __restrict__ xemb) {
    int idx = blockIdx.x * 256 + threadIdx.x;
    if (idx >= Bz * Tz * EMBz) return;
    int bt = idx / EMBz, e = idx - bt * EMBz;
    xemb[idx] = emd[(size_t)x[bt] * EMBz + e];
}

// ---- generic column-block copy (builds concatenated weight matrices) ----
__global__ void copy_cols(float* __restrict__ dst, int ldd, int dc0,
                          const float* __restrict__ src, int lds_, int sc0,
                          int rows, int cols) {
    int idx = blockIdx.x * 256 + threadIdx.x;
    if (idx >= rows * cols) return;
    int r = idx / cols, c = idx - r * cols;
    dst[(size_t)r * ldd + dc0 + c] = src[(size_t)r * lds_ + sc0 + c];
}

// ---- assemble per-step A matrices ----
__global__ void assemble_Am(float* __restrict__ A, const float* __restrict__ Hprev,
                            const float* __restrict__ qzm, const float* __restrict__ xemb, int t) {
    int idx = blockIdx.x * 256 + threadIdx.x;
    if (idx >= Bz * KAM) return;
    int b = idx / KAM, k = idx - b * KAM;
    float v;
    if (k < HMz)            v = (t > 0) ? Hprev[b * HMz + k] : 0.f;
    else if (k < HMz + Ez)  v = (t > 0) ? qzm[(size_t)b * Tz * Ez + (size_t)(t - 1) * Ez + (k - HMz)] : 0.f;
    else                    v = xemb[((size_t)b * Tz + t) * EMBz + (k - HMz - Ez)];
    A[idx] = v;
}

__global__ void assemble_Ao(float* __restrict__ A, const float* __restrict__ Hprev,
                            const float* __restrict__ qzm, const float* __restrict__ qzo,
                            const float* __restrict__ xemb, int t) {
    int idx = blockIdx.x * 256 + threadIdx.x;
    if (idx >= Bz * KAO) return;
    int b = idx / KAO, k = idx - b * KAO;
    float v;
    if (k < HOz)                 v = (t > 0) ? Hprev[b * HOz + k] : 0.f;
    else if (k < HOz + Ez)       v = qzm[(size_t)b * Tz * Ez + (size_t)t * Ez + (k - HOz)];          // current z_mask
    else if (k < HOz + 2 * Ez)   v = (t > 0) ? qzo[(size_t)b * Tz * Ez + (size_t)(t - 1) * Ez + (k - HOz - Ez)] : 0.f;
    else                         v = xemb[((size_t)b * Tz + t) * EMBz + (k - HOz - 2 * Ez)];
    A[idx] = v;
}

// ---- fp32 NT GEMM: C(M,N) = A(M,K) @ W(N,K)^T [+ bias[n]] [+ addR[m,n]] ----
// grid = (N/64, M/64), block = 256, each thread 4x4.  M,N multiples of 64; K arbitrary mult of 4.
__global__ __launch_bounds__(256) void gemm_nt64(
    const float* __restrict__ A, int lda,
    const float* __restrict__ W, int ldw,
    float* __restrict__ C, int ldc,
    int K,
    const float* __restrict__ bias,
    const float* __restrict__ addR) {
    __shared__ float As[32][68];
    __shared__ float Ws[32][68];
    const int tid = threadIdx.x;
    const int bm = blockIdx.y * 64;
    const int bn = blockIdx.x * 64;
    const int tx = tid & 15, ty = tid >> 4;
    float acc[4][4] = {};
    for (int k0 = 0; k0 < K; k0 += 32) {
#pragma unroll
        for (int i = 0; i < 8; ++i) {
            int idx = tid + i * 256;
            int m = idx >> 5, k = idx & 31;
            int gk = k0 + k;
            As[k][m] = (gk < K) ? A[(size_t)(bm + m) * lda + gk] : 0.f;
            Ws[k][m] = (gk < K) ? W[(size_t)(bn + m) * ldw + gk] : 0.f;
        }
        __syncthreads();
#pragma unroll
        for (int k = 0; k < 32; ++k) {
            float av[4], wv[4];
            *(float4*)av = *(const float4*)&As[k][ty * 4];
            *(float4*)wv = *(const float4*)&Ws[k][tx * 4];
#pragma unroll
            for (int i = 0; i < 4; ++i)
#pragma unroll
                for (int j = 0; j < 4; ++j) acc[i][j] += av[i] * wv[j];
        }
        __syncthreads();
    }
#pragma unroll
    for (int i = 0; i < 4; ++i) {
        int m = bm + ty * 4 + i;
        int n = bn + tx * 4;
        float r[4] = {acc[i][0], acc[i][1], acc[i][2], acc[i][3]};
        if (bias) {
#pragma unroll
            for (int j = 0; j < 4; ++j) r[j] += bias[n + j];
        }
        if (addR) {
            float ar[4];
            *(float4*)ar = *(const float4*)&addR[(size_t)m * ldc + n];
#pragma unroll
            for (int j = 0; j < 4; ++j) r[j] += ar[j];
        }
        *(float4*)&C[(size_t)m * ldc + n] = *(float4*)r;
    }
}

// ---- LSTM cell elementwise: gates (i,f,g,o) packed in rows of 4H ----
__global__ void lstm_cell(const float* __restrict__ g, float* __restrict__ c,
                          float* __restrict__ h_out, int H, int first) {
    int idx = blockIdx.x * 256 + threadIdx.x;
    if (idx >= Bz * H) return;
    int b = idx / H, hh = idx - b * H;
    const float* gr = g + (size_t)b * 4 * H;
    float gi = gr[hh], gf = gr[H + hh], gg = gr[2 * H + hh], go = gr[3 * H + hh];
    float cp = first ? 0.f : c[idx];
    float cn = sigf(gf) * cp + sigf(gi) * tanhf(gg);
    c[idx] = cn;
    h_out[idx] = sigf(go) * tanhf(cn);
}

// ---- KL + mask + reduce: one block per batch element ----
__global__ __launch_bounds__(256) void kl_kernel(
    const float* __restrict__ outs_m, const float* __restrict__ outs_o,
    const float* __restrict__ qmm, const float* __restrict__ qlm,
    const float* __restrict__ qmo, const float* __restrict__ qlo,
    const int* __restrict__ x, float* __restrict__ out) {
    int b = blockIdx.x;
    int tid = threadIdx.x;
    float total = 0.f;
    for (int t = 0; t < Tz; ++t) {
        int xv = x[b * Tz + t];
        if (xv == 0 || xv == 2) continue;   // seq_mask == 0 (uniform across block)
        const float* pm = outs_m + ((size_t)t * Bz + b) * 1024;
        const float* po = outs_o + ((size_t)t * Bz + b) * 1024;
        const size_t q = ((size_t)b * Tz + t) * Ez;
        for (int e = tid; e < Ez; e += 256) {
            float pmm = pm[e], plm = pm[Ez + e];
            float dm = qmm[q + e] - pmm;
            total += 0.5f * (plm - qlm[q + e]) + (__expf(qlm[q + e]) + dm * dm) / (2.f * __expf(plm)) - 0.5f;
            float pmo = po[e], plo = po[Ez + e];
            float dо = qmo[q + e] - pmo;
            total += 0.5f * (plo - qlo[q + e]) + (__expf(qlo[q + e]) + dо * dо) / (2.f * __expf(plo)) - 0.5f;
        }
    }
    __shared__ float red[256];
    red[tid] = total;
    __syncthreads();
    for (int s = 128; s > 0; s >>= 1) {
        if (tid < s) red[tid] += red[tid + s];
        __syncthreads();
    }
    if (tid == 0) out[b] = red[0];
}

extern "C" void kernel_launch(void* const* d_in, const int* in_sizes, int n_in,
                              void* d_out, int out_size, void* d_ws, size_t ws_size,
                              hipStream_t stream) {
    const float* obj_enc = (const float*)d_in[0];
    const int*   x       = (const int*)d_in[1];
    const float* qmm     = (const float*)d_in[2];
    const float* qlm     = (const float*)d_in[3];
    const float* qzm     = (const float*)d_in[4];
    const float* qmo     = (const float*)d_in[5];
    const float* qlo     = (const float*)d_in[6];
    const float* qzo     = (const float*)d_in[7];
    const float* emd     = (const float*)d_in[8];
    const float* W_ih_m  = (const float*)d_in[9];
    const float* W_hh_m  = (const float*)d_in[10];
    const float* b_m     = (const float*)d_in[11];
    const float* W_ih_o  = (const float*)d_in[12];
    const float* W_hh_o  = (const float*)d_in[13];
    const float* b_o     = (const float*)d_in[14];
    const float* fc_m_W  = (const float*)d_in[15];
    const float* fc_m_b  = (const float*)d_in[16];
    const float* fc_o_W  = (const float*)d_in[17];
    const float* fc_o_b  = (const float*)d_in[18];
    float* out = (float*)d_out;

    float* p = (float*)d_ws;
    auto alloc = [&](size_t n) { float* r = p; p += n; return r; };
    float* mask    = alloc((size_t)Bz * NOBJz);
    float* meanim  = alloc((size_t)Bz * Dz);
    float* xemb    = alloc((size_t)Bz * Tz * EMBz);
    float* Wcat_m  = alloc((size_t)4 * HMz * KAM);
    float* Wcat_o  = alloc((size_t)4 * HOz * KAO);
    float* const_m = alloc((size_t)Bz * 4 * HMz);
    float* const_o = alloc((size_t)Bz * 4 * HOz);
    float* A_m     = alloc((size_t)Bz * KAM);
    float* A_o     = alloc((size_t)Bz * KAO);
    float* g_m     = alloc((size_t)Bz * 4 * HMz);
    float* g_o     = alloc((size_t)Bz * 4 * HOz);
    float* c_m     = alloc((size_t)Bz * HMz);
    float* c_o     = alloc((size_t)Bz * HOz);
    float* H_m     = alloc((size_t)Tz * Bz * HMz);
    float* H_o     = alloc((size_t)Tz * Bz * HOz);
    float* outs_m  = alloc((size_t)Tz * Bz * 1024);
    float* outs_o  = alloc((size_t)Tz * Bz * 1024);

    // --- prologue ---
    obj_mask_kernel<<<Bz * NOBJz, 64, 0, stream>>>(obj_enc, mask);
    meanim_kernel<<<(Bz * Dz + 255) / 256, 256, 0, stream>>>(obj_enc, mask, meanim);
    embed_kernel<<<(Bz * Tz * EMBz + 255) / 256, 256, 0, stream>>>(x, emd, xemb);

    // concatenated weights: mask LSTM  [W_hh_m | W_ih_m[:,0:512) | W_ih_m[:,512:812)]
    copy_cols<<<(4096 * 1024 + 255) / 256, 256, 0, stream>>>(Wcat_m, KAM, 0,    W_hh_m, 1024, 0,   4096, 1024);
    copy_cols<<<(4096 * 512  + 255) / 256, 256, 0, stream>>>(Wcat_m, KAM, 1024, W_ih_m, 2860, 0,   4096, 512);
    copy_cols<<<(4096 * 300  + 255) / 256, 256, 0, stream>>>(Wcat_m, KAM, 1536, W_ih_m, 2860, 512, 4096, 300);
    // obj LSTM  [W_hh_o | W_ih_o[:,0:512) | W_ih_o[:,512:1024) | W_ih_o[:,1024:1324)]
    copy_cols<<<(1024 * 256 + 255) / 256, 256, 0, stream>>>(Wcat_o, KAO, 0,    W_hh_o, 256,  0,    1024, 256);
    copy_cols<<<(1024 * 512 + 255) / 256, 256, 0, stream>>>(Wcat_o, KAO, 256,  W_ih_o, 3372, 0,    1024, 512);
    copy_cols<<<(1024 * 512 + 255) / 256, 256, 0, stream>>>(Wcat_o, KAO, 768,  W_ih_o, 3372, 512,  1024, 512);
    copy_cols<<<(1024 * 300 + 255) / 256, 256, 0, stream>>>(Wcat_o, KAO, 1280, W_ih_o, 3372, 1024, 1024, 300);

    // time-invariant input projections (meanimfeats columns) + bias
    gemm_nt64<<<dim3(4096 / 64, Bz / 64), 256, 0, stream>>>(meanim, Dz, W_ih_m + 812,  2860, const_m, 4096, Dz, b_m, nullptr);
    gemm_nt64<<<dim3(1024 / 64, Bz / 64), 256, 0, stream>>>(meanim, Dz, W_ih_o + 1324, 3372, const_o, 1024, Dz, b_o, nullptr);

    // --- sequential T loop ---
    for (int t = 0; t < Tz; ++t) {
        const float* Hm_prev = H_m + (size_t)(t > 0 ? t - 1 : 0) * Bz * HMz;
        const float* Ho_prev = H_o + (size_t)(t > 0 ? t - 1 : 0) * Bz * HOz;

        assemble_Am<<<(Bz * KAM + 255) / 256, 256, 0, stream>>>(A_m, Hm_prev, qzm, xemb, t);
        gemm_nt64<<<dim3(4096 / 64, Bz / 64), 256, 0, stream>>>(A_m, KAM, Wcat_m, KAM, g_m, 4096, KAM, nullptr, const_m);
        lstm_cell<<<(Bz * HMz + 255) / 256, 256, 0, stream>>>(g_m, c_m, H_m + (size_t)t * Bz * HMz, HMz, t == 0);

        assemble_Ao<<<(Bz * KAO + 255) / 256, 256, 0, stream>>>(A_o, Ho_prev, qzm, qzo, xemb, t);
        gemm_nt64<<<dim3(1024 / 64, Bz / 64), 256, 0, stream>>>(A_o, KAO, Wcat_o, KAO, g_o, 1024, KAO, nullptr, const_o);
        lstm_cell<<<(Bz * HOz + 255) / 256, 256, 0, stream>>>(g_o, c_o, H_o + (size_t)t * Bz * HOz, HOz, t == 0);
    }

    // --- FC heads, batched over all (t, b) rows ---
    gemm_nt64<<<dim3(1024 / 64, (Tz * Bz) / 64), 256, 0, stream>>>(H_m, HMz, fc_m_W, HMz, outs_m, 1024, HMz, fc_m_b, nullptr);
    gemm_nt64<<<dim3(1024 / 64, (Tz * Bz) / 64), 256, 0, stream>>>(H_o, HOz, fc_o_W, HOz, outs_o, 1024, HOz, fc_o_b, nullptr);

    // --- KL + seq_mask + reduce ---
    kl_kernel<<<Bz, 256, 0, stream>>>(outs_m, outs_o, qmm, qlm, qmo, qlo, x, out);
}

// Round 2
// 1744.201 us; speedup vs baseline: 5.6003x; 5.6003x over previous
//
#include <hip/hip_runtime.h>

#define Bz 512
#define Tz 20
#define NOBJz 36
#define Dz 2048
#define EMBz 300
#define Ez 512
#define HMz 1024
#define HOz 256
#define KXM 832     // E + EMB = 812, padded to x64
#define KXO 1344    // 2E + EMB = 1324, padded to x64
#define LDSTRIDE 72 // 64 + 8 bf16 pad: rows 144B (16B-aligned), uniform bank spread

typedef short v8s __attribute__((ext_vector_type(8)));
typedef float v4f __attribute__((ext_vector_type(4)));

__device__ __forceinline__ float sigf(float x) { return 1.f / (1.f + __expf(-x)); }

__device__ __forceinline__ unsigned short f2bf(float f) {
    union { float f; unsigned u; } v; v.f = f;
    unsigned u = v.u;
    u += 0x7FFFu + ((u >> 16) & 1u);   // RNE
    return (unsigned short)(u >> 16);
}
__device__ __forceinline__ float bf2f(unsigned short h) {
    union { unsigned u; float f; } v; v.u = ((unsigned)h) << 16;
    return v.f;
}

// ---- obj mask: one wave per (b,n), reduce |.| over D ----
__global__ void obj_mask_kernel(const float* __restrict__ obj_enc, float* __restrict__ mask) {
    int bn = blockIdx.x;
    int lane = threadIdx.x;
    const float* row = obj_enc + (size_t)bn * Dz;
    float s = 0.f;
    for (int d = lane; d < Dz; d += 64) s += fabsf(row[d]);
    for (int off = 32; off > 0; off >>= 1) s += __shfl_down(s, off);
    if (lane == 0) mask[bn] = (s > 0.f) ? 1.f : 0.f;
}

// ---- meanimfeats -> bf16 ----
__global__ void meanim_kernel(const float* __restrict__ obj_enc, const float* __restrict__ mask,
                              unsigned short* __restrict__ meanim_bf) {
    int idx = blockIdx.x * 256 + threadIdx.x;
    if (idx >= Bz * Dz) return;
    int b = idx / Dz, d = idx - b * Dz;
    float s = 0.f, cnt = 0.f;
    for (int n = 0; n < NOBJz; ++n) {
        float m = mask[b * NOBJz + n];
        cnt += m;
        s += obj_enc[((size_t)b * NOBJz + n) * Dz + d] * m;
    }
    meanim_bf[idx] = f2bf(s / fmaxf(cnt, 1e-9f));
}

// ---- fp32 -> bf16 weight conversion with column slice + zero pad ----
__global__ void convert_pad(unsigned short* __restrict__ dst, const float* __restrict__ src,
                            int rows, int src_cols, int ld_src, int col0, int dst_ld) {
    int idx = blockIdx.x * 256 + threadIdx.x;
    if (idx >= rows * dst_ld) return;
    int r = idx / dst_ld, c = idx - r * dst_ld;
    dst[idx] = (c < src_cols) ? f2bf(src[(size_t)r * ld_src + col0 + c]) : (unsigned short)0;
}

// ---- assemble time-varying inputs, row r = t*B + b ----
__global__ void assemble_Xm(unsigned short* __restrict__ X, const float* __restrict__ qzm,
                            const int* __restrict__ x, const float* __restrict__ emd) {
    int idx = blockIdx.x * 256 + threadIdx.x;
    if (idx >= Tz * Bz * KXM) return;
    int r = idx / KXM, c = idx - r * KXM;
    int t = r / Bz, b = r - t * Bz;
    float v;
    if (c < Ez)            v = (t > 0) ? qzm[((size_t)b * Tz + (t - 1)) * Ez + c] : 0.f;
    else if (c < Ez + EMBz) { int xv = x[b * Tz + t]; v = emd[(size_t)xv * EMBz + (c - Ez)]; }
    else                    v = 0.f;
    X[idx] = f2bf(v);
}

__global__ void assemble_Xo(unsigned short* __restrict__ X, const float* __restrict__ qzm,
                            const float* __restrict__ qzo, const int* __restrict__ x,
                            const float* __restrict__ emd) {
    int idx = blockIdx.x * 256 + threadIdx.x;
    if (idx >= Tz * Bz * KXO) return;
    int r = idx / KXO, c = idx - r * KXO;
    int t = r / Bz, b = r - t * Bz;
    float v;
    if (c < Ez)                 v = qzm[((size_t)b * Tz + t) * Ez + c];                      // current z_mask
    else if (c < 2 * Ez)        v = (t > 0) ? qzo[((size_t)b * Tz + (t - 1)) * Ez + (c - Ez)] : 0.f;
    else if (c < 2 * Ez + EMBz) { int xv = x[b * Tz + t]; v = emd[(size_t)xv * EMBz + (c - 2 * Ez)]; }
    else                        v = 0.f;
    X[idx] = f2bf(v);
}

// ---- bf16 MFMA GEMM core: C(M,N) = A(M,K) @ W(N,K)^T (+bias) (+addR bf16) ----
// block 256 = 4 waves; tile BM=64 x BN=128; wave w covers n in [w*32, w*32+32)
__device__ __forceinline__ void gemm_body(
    int bm, int bn,
    const unsigned short* __restrict__ A, int lda,
    const unsigned short* __restrict__ W, int ldw,
    void* __restrict__ Cv, int ldc, int K,
    const float* __restrict__ bias,
    const unsigned short* __restrict__ addR, unsigned addR_mask, int out_bf16,
    unsigned short* As, unsigned short* Ws) {
    const int tid = threadIdx.x;
    const int lane = tid & 63, w = tid >> 6;
    const int r15 = lane & 15, quad = lane >> 4;
    v4f acc[4][2] = {};
    for (int k0 = 0; k0 < K; k0 += 64) {
#pragma unroll
        for (int it = 0; it < 2; ++it) {         // A: 64 rows x 8 segs of 8 bf16
            int idx = tid + it * 256;
            int r = idx >> 3, c = idx & 7;
            *(v8s*)&As[r * LDSTRIDE + c * 8] = *(const v8s*)&A[(size_t)(bm + r) * lda + k0 + c * 8];
        }
#pragma unroll
        for (int it = 0; it < 4; ++it) {         // B: 128 rows x 8 segs
            int idx = tid + it * 256;
            int r = idx >> 3, c = idx & 7;
            *(v8s*)&Ws[r * LDSTRIDE + c * 8] = *(const v8s*)&W[(size_t)(bn + r) * ldw + k0 + c * 8];
        }
        __syncthreads();
#pragma unroll
        for (int kk = 0; kk < 64; kk += 32) {
            v8s a[4], b[2];
#pragma unroll
            for (int i = 0; i < 4; ++i)
                a[i] = *(const v8s*)&As[(16 * i + r15) * LDSTRIDE + kk + quad * 8];
#pragma unroll
            for (int j = 0; j < 2; ++j)
                b[j] = *(const v8s*)&Ws[(w * 32 + 16 * j + r15) * LDSTRIDE + kk + quad * 8];
#pragma unroll
            for (int i = 0; i < 4; ++i)
#pragma unroll
                for (int j = 0; j < 2; ++j)
                    acc[i][j] = __builtin_amdgcn_mfma_f32_16x16x32_bf16(a[i], b[j], acc[i][j], 0, 0, 0);
        }
        __syncthreads();
    }
    float* Cf = (float*)Cv;
    unsigned short* Cb = (unsigned short*)Cv;
#pragma unroll
    for (int i = 0; i < 4; ++i) {
#pragma unroll
        for (int j = 0; j < 2; ++j) {
            int col = bn + w * 32 + 16 * j + r15;
            float bv = bias ? bias[col] : 0.f;
#pragma unroll
            for (int r = 0; r < 4; ++r) {
                int row = bm + 16 * i + quad * 4 + r;
                float v = acc[i][j][r] + bv;
                if (addR) v += bf2f(addR[(size_t)(row & addR_mask) * ldc + col]);
                if (out_bf16) Cb[(size_t)row * ldc + col] = f2bf(v);
                else          Cf[(size_t)row * ldc + col] = v;
            }
        }
    }
}

__global__ __launch_bounds__(256) void gemm_bf16(
    const unsigned short* __restrict__ A, int lda,
    const unsigned short* __restrict__ W, int ldw,
    void* __restrict__ Cv, int ldc, int K,
    const float* __restrict__ bias,
    const unsigned short* __restrict__ addR, unsigned addR_mask, int out_bf16) {
    __shared__ unsigned short As[64 * LDSTRIDE];
    __shared__ unsigned short Ws[128 * LDSTRIDE];
    gemm_body(blockIdx.y * 64, blockIdx.x * 128, A, lda, W, ldw, Cv, ldc, K,
              bias, addR, addR_mask, out_bf16, As, Ws);
}

// ---- fused per-step recurrence GEMMs: blocks [0,256) = mask LSTM, [256,320) = obj LSTM ----
__global__ __launch_bounds__(256) void gemm_step(
    const unsigned short* __restrict__ Hm, const unsigned short* __restrict__ Whh_m,
    const unsigned short* __restrict__ Ginp_m, float* __restrict__ g_m,
    const unsigned short* __restrict__ Ho, const unsigned short* __restrict__ Whh_o,
    const unsigned short* __restrict__ Ginp_o, float* __restrict__ g_o) {
    __shared__ unsigned short As[64 * LDSTRIDE];
    __shared__ unsigned short Ws[128 * LDSTRIDE];
    int bx = blockIdx.x;
    if (bx < 256) {
        int bm = (bx >> 5) * 64, bn = (bx & 31) * 128;
        gemm_body(bm, bn, Hm, HMz, Whh_m, HMz, g_m, 4 * HMz, HMz, nullptr, Ginp_m, 0xFFFFFFFFu, 0, As, Ws);
    } else {
        int i = bx - 256;
        int bm = (i >> 3) * 64, bn = (i & 7) * 128;
        gemm_body(bm, bn, Ho, HOz, Whh_o, HOz, g_o, 4 * HOz, HOz, nullptr, Ginp_o, 0xFFFFFFFFu, 0, As, Ws);
    }
}

// ---- fused LSTM cells (mask + obj). first: gates come from bf16 Ginp (h_prev = 0) ----
__global__ void lstm_cell_fused(
    const float* __restrict__ gm, const unsigned short* __restrict__ gmbf,
    float* __restrict__ cm, unsigned short* __restrict__ hm,
    const float* __restrict__ go_, const unsigned short* __restrict__ gobf,
    float* __restrict__ co, unsigned short* __restrict__ ho, int first) {
    int idx = blockIdx.x * 256 + threadIdx.x;
    if (idx < Bz * HMz) {
        int b = idx / HMz, hh = idx - b * HMz;
        size_t base = (size_t)b * 4 * HMz;
        float gi, gf, gg, go;
        if (first) { gi = bf2f(gmbf[base + hh]); gf = bf2f(gmbf[base + HMz + hh]);
                     gg = bf2f(gmbf[base + 2 * HMz + hh]); go = bf2f(gmbf[base + 3 * HMz + hh]); }
        else       { gi = gm[base + hh]; gf = gm[base + HMz + hh];
                     gg = gm[base + 2 * HMz + hh]; go = gm[base + 3 * HMz + hh]; }
        float cp = first ? 0.f : cm[idx];
        float cn = sigf(gf) * cp + sigf(gi) * tanhf(gg);
        cm[idx] = cn;
        hm[idx] = f2bf(sigf(go) * tanhf(cn));
    } else {
        idx -= Bz * HMz;
        if (idx >= Bz * HOz) return;
        int b = idx / HOz, hh = idx - b * HOz;
        size_t base = (size_t)b * 4 * HOz;
        float gi, gf, gg, go;
        if (first) { gi = bf2f(gobf[base + hh]); gf = bf2f(gobf[base + HOz + hh]);
                     gg = bf2f(gobf[base + 2 * HOz + hh]); go = bf2f(gobf[base + 3 * HOz + hh]); }
        else       { gi = go_[base + hh]; gf = go_[base + HOz + hh];
                     gg = go_[base + 2 * HOz + hh]; go = go_[base + 3 * HOz + hh]; }
        float cp = first ? 0.f : co[idx];
        float cn = sigf(gf) * cp + sigf(gi) * tanhf(gg);
        co[idx] = cn;
        ho[idx] = f2bf(sigf(go) * tanhf(cn));
    }
}

// ---- KL + mask + reduce: one block per batch element; outs rows r = t*B + b ----
__global__ __launch_bounds__(256) void kl_kernel(
    const float* __restrict__ outs_m, const float* __restrict__ outs_o,
    const float* __restrict__ qmm, const float* __restrict__ qlm,
    const float* __restrict__ qmo, const float* __restrict__ qlo,
    const int* __restrict__ x, float* __restrict__ out) {
    int b = blockIdx.x;
    int tid = threadIdx.x;
    float total = 0.f;
    for (int t = 0; t < Tz; ++t) {
        int xv = x[b * Tz + t];
        if (xv == 0 || xv == 2) continue;
        const float* pm = outs_m + ((size_t)t * Bz + b) * 1024;
        const float* po = outs_o + ((size_t)t * Bz + b) * 1024;
        const size_t q = ((size_t)b * Tz + t) * Ez;
        for (int e = tid; e < Ez; e += 256) {
            float pmm = pm[e], plm = pm[Ez + e];
            float dm = qmm[q + e] - pmm;
            total += 0.5f * (plm - qlm[q + e]) + (__expf(qlm[q + e]) + dm * dm) / (2.f * __expf(plm)) - 0.5f;
            float pmo = po[e], plo = po[Ez + e];
            float dn = qmo[q + e] - pmo;
            total += 0.5f * (plo - qlo[q + e]) + (__expf(qlo[q + e]) + dn * dn) / (2.f * __expf(plo)) - 0.5f;
        }
    }
    __shared__ float red[256];
    red[tid] = total;
    __syncthreads();
    for (int s = 128; s > 0; s >>= 1) {
        if (tid < s) red[tid] += red[tid + s];
        __syncthreads();
    }
    if (tid == 0) out[b] = red[0];
}

extern "C" void kernel_launch(void* const* d_in, const int* in_sizes, int n_in,
                              void* d_out, int out_size, void* d_ws, size_t ws_size,
                              hipStream_t stream) {
    const float* obj_enc = (const float*)d_in[0];
    const int*   x       = (const int*)d_in[1];
    const float* qmm     = (const float*)d_in[2];
    const float* qlm     = (const float*)d_in[3];
    const float* qzm     = (const float*)d_in[4];
    const float* qmo     = (const float*)d_in[5];
    const float* qlo     = (const float*)d_in[6];
    const float* qzo     = (const float*)d_in[7];
    const float* emd     = (const float*)d_in[8];
    const float* W_ih_m  = (const float*)d_in[9];
    const float* W_hh_m  = (const float*)d_in[10];
    const float* b_m     = (const float*)d_in[11];
    const float* W_ih_o  = (const float*)d_in[12];
    const float* W_hh_o  = (const float*)d_in[13];
    const float* b_o     = (const float*)d_in[14];
    const float* fc_m_W  = (const float*)d_in[15];
    const float* fc_m_b  = (const float*)d_in[16];
    const float* fc_o_W  = (const float*)d_in[17];
    const float* fc_o_b  = (const float*)d_in[18];
    float* out = (float*)d_out;

    // ---- workspace layout (256B aligned slices) ----
    char* base = (char*)d_ws;
    size_t off = 0;
    auto alloc = [&](size_t bytes) { char* r = base + off; off += (bytes + 255) & ~(size_t)255; return r; };
    typedef unsigned short u16;
    float* mask     = (float*)alloc((size_t)Bz * NOBJz * 4);
    u16* meanim_bf  = (u16*)alloc((size_t)Bz * Dz * 2);
    u16* Whh_m_bf   = (u16*)alloc((size_t)4 * HMz * HMz * 2);
    u16* Whh_o_bf   = (u16*)alloc((size_t)4 * HOz * HOz * 2);
    u16* Winp_m_bf  = (u16*)alloc((size_t)4 * HMz * KXM * 2);
    u16* Winp_o_bf  = (u16*)alloc((size_t)4 * HOz * KXO * 2);
    u16* Wmean_m_bf = (u16*)alloc((size_t)4 * HMz * Dz * 2);
    u16* Wmean_o_bf = (u16*)alloc((size_t)4 * HOz * Dz * 2);
    u16* Wfc_m_bf   = (u16*)alloc((size_t)1024 * HMz * 2);
    u16* Wfc_o_bf   = (u16*)alloc((size_t)1024 * HOz * 2);
    u16* Xin_m      = (u16*)alloc((size_t)Tz * Bz * KXM * 2);
    u16* Xin_o      = (u16*)alloc((size_t)Tz * Bz * KXO * 2);
    u16* const_m_bf = (u16*)alloc((size_t)Bz * 4 * HMz * 2);
    u16* const_o_bf = (u16*)alloc((size_t)Bz * 4 * HOz * 2);
    u16* Ginp_m_bf  = (u16*)alloc((size_t)Tz * Bz * 4 * HMz * 2);   // 84 MB; reused as outs after loop
    u16* Ginp_o_bf  = (u16*)alloc((size_t)Tz * Bz * 4 * HOz * 2);
    float* g_m      = (float*)alloc((size_t)Bz * 4 * HMz * 4);
    float* g_o      = (float*)alloc((size_t)Bz * 4 * HOz * 4);
    float* c_m      = (float*)alloc((size_t)Bz * HMz * 4);
    float* c_o      = (float*)alloc((size_t)Bz * HOz * 4);
    u16* H_m        = (u16*)alloc((size_t)Tz * Bz * HMz * 2);
    u16* H_o        = (u16*)alloc((size_t)Tz * Bz * HOz * 2);
    // outs alias the (consumed-by-then) Ginp_m region: 2 x 41.9 MB inside 83.9 MB
    float* outs_m = (float*)Ginp_m_bf;
    float* outs_o = outs_m + (size_t)Tz * Bz * 1024;

    const int TB = Tz * Bz;   // 10240

    // ---- prologue: mask / mean / input assembly / weight conversion ----
    obj_mask_kernel<<<Bz * NOBJz, 64, 0, stream>>>(obj_enc, mask);
    meanim_kernel<<<(Bz * Dz + 255) / 256, 256, 0, stream>>>(obj_enc, mask, meanim_bf);
    assemble_Xm<<<(TB * KXM + 255) / 256, 256, 0, stream>>>(Xin_m, qzm, x, emd);
    assemble_Xo<<<(TB * KXO + 255) / 256, 256, 0, stream>>>(Xin_o, qzm, qzo, x, emd);

    convert_pad<<<(4 * HMz * HMz + 255) / 256, 256, 0, stream>>>(Whh_m_bf, W_hh_m, 4 * HMz, HMz, HMz, 0, HMz);
    convert_pad<<<(4 * HOz * HOz + 255) / 256, 256, 0, stream>>>(Whh_o_bf, W_hh_o, 4 * HOz, HOz, HOz, 0, HOz);
    convert_pad<<<(4 * HMz * KXM + 255) / 256, 256, 0, stream>>>(Winp_m_bf, W_ih_m, 4 * HMz, Ez + EMBz, 2860, 0, KXM);
    convert_pad<<<(4 * HOz * KXO + 255) / 256, 256, 0, stream>>>(Winp_o_bf, W_ih_o, 4 * HOz, 2 * Ez + EMBz, 3372, 0, KXO);
    convert_pad<<<(4 * HMz * Dz + 255) / 256, 256, 0, stream>>>(Wmean_m_bf, W_ih_m, 4 * HMz, Dz, 2860, Ez + EMBz, Dz);
    convert_pad<<<(4 * HOz * Dz + 255) / 256, 256, 0, stream>>>(Wmean_o_bf, W_ih_o, 4 * HOz, Dz, 3372, 2 * Ez + EMBz, Dz);
    convert_pad<<<(1024 * HMz + 255) / 256, 256, 0, stream>>>(Wfc_m_bf, fc_m_W, 1024, HMz, HMz, 0, HMz);
    convert_pad<<<(1024 * HOz + 255) / 256, 256, 0, stream>>>(Wfc_o_bf, fc_o_W, 1024, HOz, HOz, 0, HOz);

    // ---- const = bias + meanim-projection (bf16 out) ----
    gemm_bf16<<<dim3(4 * HMz / 128, Bz / 64), 256, 0, stream>>>(
        meanim_bf, Dz, Wmean_m_bf, Dz, const_m_bf, 4 * HMz, Dz, b_m, nullptr, 0u, 1);
    gemm_bf16<<<dim3(4 * HOz / 128, Bz / 64), 256, 0, stream>>>(
        meanim_bf, Dz, Wmean_o_bf, Dz, const_o_bf, 4 * HOz, Dz, b_o, nullptr, 0u, 1);

    // ---- Ginp = Xin @ Winp^T + const (all T at once; row r = t*B + b, addR row = r & 511) ----
    gemm_bf16<<<dim3(4 * HMz / 128, TB / 64), 256, 0, stream>>>(
        Xin_m, KXM, Winp_m_bf, KXM, Ginp_m_bf, 4 * HMz, KXM, nullptr, const_m_bf, (unsigned)(Bz - 1), 1);
    gemm_bf16<<<dim3(4 * HOz / 128, TB / 64), 256, 0, stream>>>(
        Xin_o, KXO, Winp_o_bf, KXO, Ginp_o_bf, 4 * HOz, KXO, nullptr, const_o_bf, (unsigned)(Bz - 1), 1);

    // ---- sequential T loop: only h @ W_hh remains ----
    for (int t = 0; t < Tz; ++t) {
        const u16* Gm_t = Ginp_m_bf + (size_t)t * Bz * 4 * HMz;
        const u16* Go_t = Ginp_o_bf + (size_t)t * Bz * 4 * HOz;
        if (t > 0) {
            const u16* Hm_prev = H_m + (size_t)(t - 1) * Bz * HMz;
            const u16* Ho_prev = H_o + (size_t)(t - 1) * Bz * HOz;
            gemm_step<<<320, 256, 0, stream>>>(Hm_prev, Whh_m_bf, Gm_t, g_m,
                                               Ho_prev, Whh_o_bf, Go_t, g_o);
        }
        lstm_cell_fused<<<(Bz * (HMz + HOz) + 255) / 256, 256, 0, stream>>>(
            g_m, Gm_t, c_m, H_m + (size_t)t * Bz * HMz,
            g_o, Go_t, c_o, H_o + (size_t)t * Bz * HOz, t == 0);
    }

    // ---- FC heads batched over all (t,b) rows ----
    gemm_bf16<<<dim3(1024 / 128, TB / 64), 256, 0, stream>>>(
        H_m, HMz, Wfc_m_bf, HMz, outs_m, 1024, HMz, fc_m_b, nullptr, 0u, 0);
    gemm_bf16<<<dim3(1024 / 128, TB / 64), 256, 0, stream>>>(
        H_o, HOz, Wfc_o_bf, HOz, outs_o, 1024, HOz, fc_o_b, nullptr, 0u, 0);

    // ---- KL + seq_mask + reduce ----
    kl_kernel<<<Bz, 256, 0, stream>>>(outs_m, outs_o, qmm, qlm, qmo, qlo, x, out);
}

// Round 3
// 1341.995 us; speedup vs baseline: 7.2788x; 1.2997x over previous
//
#include <hip/hip_runtime.h>

#define Bz 512
#define Tz 20
#define NOBJz 36
#define Dz 2048
#define EMBz 300
#define Ez 512
#define HMz 1024
#define HOz 256
#define KXM 832     // E + EMB = 812 padded to x64
#define KXO 1344    // 2E + EMB = 1324 padded to x64

typedef short v8s __attribute__((ext_vector_type(8)));
typedef float v4f __attribute__((ext_vector_type(4)));
typedef unsigned short u16;

__device__ __forceinline__ float sigf(float x) { return 1.f / (1.f + __expf(-x)); }
__device__ __forceinline__ float tanhfast(float x) { return 2.f * sigf(2.f * x) - 1.f; }

__device__ __forceinline__ u16 f2bf(float f) {
    union { float f; unsigned u; } v; v.f = f;
    unsigned u = v.u;
    u += 0x7FFFu + ((u >> 16) & 1u);   // RNE
    return (u16)(u >> 16);
}
__device__ __forceinline__ float bf2f(u16 h) {
    union { unsigned u; float f; } v; v.u = ((unsigned)h) << 16;
    return v.f;
}

// =================== prologue kernels ===================

__global__ void obj_mask_kernel(const float* __restrict__ obj_enc, float* __restrict__ mask) {
    int bn = blockIdx.x, lane = threadIdx.x;
    const float* row = obj_enc + (size_t)bn * Dz;
    float s = 0.f;
    for (int d = lane; d < Dz; d += 64) s += fabsf(row[d]);
    for (int off = 32; off > 0; off >>= 1) s += __shfl_down(s, off);
    if (lane == 0) mask[bn] = (s > 0.f) ? 1.f : 0.f;
}

__global__ void meanim_kernel(const float* __restrict__ obj_enc, const float* __restrict__ mask,
                              u16* __restrict__ meanim_bf) {
    int idx = blockIdx.x * 256 + threadIdx.x;
    if (idx >= Bz * Dz) return;
    int b = idx / Dz, d = idx - b * Dz;
    float s = 0.f, cnt = 0.f;
    for (int n = 0; n < NOBJz; ++n) {
        float m = mask[b * NOBJz + n];
        cnt += m;
        s += obj_enc[((size_t)b * NOBJz + n) * Dz + d] * m;
    }
    meanim_bf[idx] = f2bf(s / fmaxf(cnt, 1e-9f));
}

// fp32 -> bf16 weight convert, optional column slice, zero pad, optional gate-interleave
// row permutation: dst row r' <- src row g*permH + u with g=(r'>>4)&3, u=(r'>>6)*16+(r'&15)
__global__ void convert_pad(u16* __restrict__ dst, const float* __restrict__ src,
                            int rows, int src_cols, int ld_src, int col0, int dst_ld, int permH) {
    int idx = blockIdx.x * 256 + threadIdx.x;
    if (idx >= rows * dst_ld) return;
    int rp = idx / dst_ld, c = idx - rp * dst_ld;
    int n = rp;
    if (permH) { int g = (rp >> 4) & 3, u = (rp >> 6) * 16 + (rp & 15); n = g * permH + u; }
    dst[idx] = (c < src_cols) ? f2bf(src[(size_t)n * ld_src + col0 + c]) : (u16)0;
}

__global__ void bias_perm(float* __restrict__ dst, const float* __restrict__ src, int H) {
    int r = blockIdx.x * 256 + threadIdx.x;
    if (r >= 4 * H) return;
    int g = (r >> 4) & 3, u = (r >> 6) * 16 + (r & 15);
    dst[r] = src[g * H + u];
}

__global__ void assemble_Xm(u16* __restrict__ X, const float* __restrict__ qzm,
                            const int* __restrict__ x, const float* __restrict__ emd) {
    int idx = blockIdx.x * 256 + threadIdx.x;
    if (idx >= Tz * Bz * KXM) return;
    int r = idx / KXM, c = idx - r * KXM;
    int t = r / Bz, b = r - t * Bz;
    float v;
    if (c < Ez)             v = (t > 0) ? qzm[((size_t)b * Tz + (t - 1)) * Ez + c] : 0.f;
    else if (c < Ez + EMBz) { int xv = x[b * Tz + t]; v = emd[(size_t)xv * EMBz + (c - Ez)]; }
    else                    v = 0.f;
    X[idx] = f2bf(v);
}

__global__ void assemble_Xo(u16* __restrict__ X, const float* __restrict__ qzm,
                            const float* __restrict__ qzo, const int* __restrict__ x,
                            const float* __restrict__ emd) {
    int idx = blockIdx.x * 256 + threadIdx.x;
    if (idx >= Tz * Bz * KXO) return;
    int r = idx / KXO, c = idx - r * KXO;
    int t = r / Bz, b = r - t * Bz;
    float v;
    if (c < Ez)                 v = qzm[((size_t)b * Tz + t) * Ez + c];
    else if (c < 2 * Ez)        v = (t > 0) ? qzo[((size_t)b * Tz + (t - 1)) * Ez + (c - Ez)] : 0.f;
    else if (c < 2 * Ez + EMBz) { int xv = x[b * Tz + t]; v = emd[(size_t)xv * EMBz + (c - 2 * Ez)]; }
    else                        v = 0.f;
    X[idx] = f2bf(v);
}

// =================== MFMA GEMM core (128x128 tile, BK=64, global_load_lds, XOR swizzle) ===================
// LDS tile: 128 rows x 64 bf16, row-major stride 64; 8-elem chunk p of row r holds
// logical k-chunk (p ^ (r&7)).  Staged with global_load_lds width=16 (lane-contiguous).
// 4 waves as 2(M) x 2(N), each 64x64 via 4x4 MFMA 16x16x32 accumulators.

__device__ __forceinline__ void mma128(
    const u16* __restrict__ A, int lda, const u16* __restrict__ W, int ldw, int K,
    int bm, int bn, u16* As, u16* Ws, v4f (&acc)[4][4]) {
    const int tid = threadIdx.x;
    const int lane = tid & 63, w = tid >> 6;
    const int wm = w >> 1, wn = w & 1;
    const int r15 = lane & 15, quad = lane >> 4;
    const int lrow = lane >> 3;                 // 0..7 within chunk
    const int lcol = ((lane & 7) ^ lrow) * 8;   // swizzled source column (elements)
    for (int k0 = 0; k0 < K; k0 += 64) {
        const u16* gA = A + (size_t)bm * lda + k0;
        const u16* gW = W + (size_t)bn * ldw + k0;
#pragma unroll
        for (int c = 0; c < 4; ++c) {
            int chunk = w * 4 + c;              // 16 chunks of 8 rows each
            int row = chunk * 8 + lrow;
            __builtin_amdgcn_global_load_lds(
                (const __attribute__((address_space(1))) unsigned int*)(gA + (size_t)row * lda + lcol),
                (__attribute__((address_space(3))) unsigned int*)(As + chunk * 512), 16, 0, 0);
            __builtin_amdgcn_global_load_lds(
                (const __attribute__((address_space(1))) unsigned int*)(gW + (size_t)row * ldw + lcol),
                (__attribute__((address_space(3))) unsigned int*)(Ws + chunk * 512), 16, 0, 0);
        }
        __syncthreads();
#pragma unroll
        for (int kk = 0; kk < 64; kk += 32) {
            v8s a[4], b[4];
#pragma unroll
            for (int i = 0; i < 4; ++i) {
                int r = wm * 64 + 16 * i + r15;
                a[i] = *(const v8s*)&As[r * 64 + (((kk >> 3) + quad) ^ (r15 & 7)) * 8];
            }
#pragma unroll
            for (int j = 0; j < 4; ++j) {
                int r = wn * 64 + 16 * j + r15;
                b[j] = *(const v8s*)&Ws[r * 64 + (((kk >> 3) + quad) ^ (r15 & 7)) * 8];
            }
#pragma unroll
            for (int i = 0; i < 4; ++i)
#pragma unroll
                for (int j = 0; j < 4; ++j)
                    acc[i][j] = __builtin_amdgcn_mfma_f32_16x16x32_bf16(a[i], b[j], acc[i][j], 0, 0, 0);
        }
        __syncthreads();
    }
}

// generic GEMM: C(M,N) = A @ W^T (+bias[col]) (+addR bf16[row&mask][col]) ; out fp32 or bf16
__global__ __launch_bounds__(256) void gemm128(
    const u16* __restrict__ A, int lda, const u16* __restrict__ W, int ldw,
    void* __restrict__ Cv, int ldc, int K,
    const float* __restrict__ bias, const u16* __restrict__ addR, unsigned addR_mask, int out_bf16) {
    __shared__ u16 As[128 * 64];
    __shared__ u16 Ws[128 * 64];
    v4f acc[4][4] = {};
    const int bm = blockIdx.y * 128, bn = blockIdx.x * 128;
    mma128(A, lda, W, ldw, K, bm, bn, As, Ws, acc);
    const int tid = threadIdx.x, lane = tid & 63, w = tid >> 6;
    const int wm = w >> 1, wn = w & 1, r15 = lane & 15, quad = lane >> 4;
    float* Cf = (float*)Cv;
    u16* Cb = (u16*)Cv;
#pragma unroll
    for (int i = 0; i < 4; ++i)
#pragma unroll
        for (int j = 0; j < 4; ++j) {
            int col = bn + wn * 64 + 16 * j + r15;
            float bv = bias ? bias[col] : 0.f;
#pragma unroll
            for (int r = 0; r < 4; ++r) {
                int row = bm + wm * 64 + 16 * i + quad * 4 + r;
                float v = acc[i][j][r] + bv;
                if (addR) v += bf2f(addR[(size_t)(row & addR_mask) * ldc + col]);
                if (out_bf16) Cb[(size_t)row * ldc + col] = f2bf(v);
                else          Cf[(size_t)row * ldc + col] = v;
            }
        }
}

// fused step: g = h_prev @ Whh^T + Ginp(permuted), then LSTM cell in-register.
// Gate interleave means wave's j index IS the gate (i,f,g,o) for unit ((bn+wn*64)>>6)*16 + r15.
// blocks [0,128): mask LSTM (N=4096, K=1024); blocks [128,160): obj LSTM (N=1024, K=256)
__global__ __launch_bounds__(256) void step_fused(
    const u16* __restrict__ Hm_prev, const u16* __restrict__ Whh_m, const u16* __restrict__ Gm,
    float* __restrict__ cm, u16* __restrict__ hm,
    const u16* __restrict__ Ho_prev, const u16* __restrict__ Whh_o, const u16* __restrict__ Go,
    float* __restrict__ co, u16* __restrict__ ho) {
    __shared__ u16 As[128 * 64];
    __shared__ u16 Ws[128 * 64];
    v4f acc[4][4] = {};
    const int bx = blockIdx.x;
    const u16 *A, *W, *G;
    float* c;
    u16* h;
    int lda, N4, H, bm, bn, K;
    if (bx < 128) {
        bm = (bx >> 5) * 128; bn = (bx & 31) * 128;
        A = Hm_prev; W = Whh_m; G = Gm; c = cm; h = hm; lda = HMz; N4 = 4 * HMz; H = HMz; K = HMz;
    } else {
        int lx = bx - 128;
        bm = (lx >> 3) * 128; bn = (lx & 7) * 128;
        A = Ho_prev; W = Whh_o; G = Go; c = co; h = ho; lda = HOz; N4 = 4 * HOz; H = HOz; K = HOz;
    }
    mma128(A, lda, W, lda, K, bm, bn, As, Ws, acc);
    const int tid = threadIdx.x, lane = tid & 63, w = tid >> 6;
    const int wm = w >> 1, wn = w & 1, r15 = lane & 15, quad = lane >> 4;
    const int u = ((bn + wn * 64) >> 6) * 16 + r15;
#pragma unroll
    for (int i = 0; i < 4; ++i)
#pragma unroll
        for (int r = 0; r < 4; ++r) {
            int b = bm + wm * 64 + 16 * i + quad * 4 + r;
            size_t gb = (size_t)b * N4 + bn + wn * 64 + r15;
            float gi = acc[i][0][r] + bf2f(G[gb]);
            float gf = acc[i][1][r] + bf2f(G[gb + 16]);
            float gg = acc[i][2][r] + bf2f(G[gb + 32]);
            float go = acc[i][3][r] + bf2f(G[gb + 48]);
            size_t ci = (size_t)b * H + u;
            float cn = sigf(gf) * c[ci] + sigf(gi) * tanhfast(gg);
            c[ci] = cn;
            h[ci] = f2bf(sigf(go) * tanhfast(cn));
        }
}

// t=0 cell: gates = Ginp only (h_prev = 0, c_prev = 0); Ginp is gate-interleaved
__global__ void cell0(const u16* __restrict__ Gm, float* __restrict__ cm, u16* __restrict__ hm,
                      const u16* __restrict__ Go, float* __restrict__ co, u16* __restrict__ ho) {
    int idx = blockIdx.x * 256 + threadIdx.x;
    if (idx < Bz * HMz) {
        int b = idx / HMz, u = idx - b * HMz;
        size_t gb = (size_t)b * 4 * HMz + ((u >> 4) * 64 + (u & 15));
        float gi = bf2f(Gm[gb]), gf = bf2f(Gm[gb + 16]), gg = bf2f(Gm[gb + 32]), go = bf2f(Gm[gb + 48]);
        (void)gf;
        float cn = sigf(gi) * tanhfast(gg);
        cm[idx] = cn;
        hm[idx] = f2bf(sigf(go) * tanhfast(cn));
    } else {
        idx -= Bz * HMz;
        if (idx >= Bz * HOz) return;
        int b = idx / HOz, u = idx - b * HOz;
        size_t gb = (size_t)b * 4 * HOz + ((u >> 4) * 64 + (u & 15));
        float gi = bf2f(Go[gb]), gg = bf2f(Go[gb + 32]), go = bf2f(Go[gb + 48]);
        float cn = sigf(gi) * tanhfast(gg);
        co[idx] = cn;
        ho[idx] = f2bf(sigf(go) * tanhfast(cn));
    }
}

// =================== KL reduce ===================
__global__ __launch_bounds__(256) void kl_kernel(
    const float* __restrict__ outs_m, const float* __restrict__ outs_o,
    const float* __restrict__ qmm, const float* __restrict__ qlm,
    const float* __restrict__ qmo, const float* __restrict__ qlo,
    const int* __restrict__ x, float* __restrict__ out) {
    int b = blockIdx.x, tid = threadIdx.x;
    float total = 0.f;
    for (int t = 0; t < Tz; ++t) {
        int xv = x[b * Tz + t];
        if (xv == 0 || xv == 2) continue;
        const float* pm = outs_m + ((size_t)t * Bz + b) * 1024;
        const float* po = outs_o + ((size_t)t * Bz + b) * 1024;
        const size_t q = ((size_t)b * Tz + t) * Ez;
        for (int e = tid; e < Ez; e += 256) {
            float pmm = pm[e], plm = pm[Ez + e];
            float dm = qmm[q + e] - pmm;
            total += 0.5f * (plm - qlm[q + e]) + (__expf(qlm[q + e]) + dm * dm) / (2.f * __expf(plm)) - 0.5f;
            float pmo = po[e], plo = po[Ez + e];
            float dn = qmo[q + e] - pmo;
            total += 0.5f * (plo - qlo[q + e]) + (__expf(qlo[q + e]) + dn * dn) / (2.f * __expf(plo)) - 0.5f;
        }
    }
    __shared__ float red[256];
    red[tid] = total;
    __syncthreads();
    for (int s = 128; s > 0; s >>= 1) {
        if (tid < s) red[tid] += red[tid + s];
        __syncthreads();
    }
    if (tid == 0) out[b] = red[0];
}

extern "C" void kernel_launch(void* const* d_in, const int* in_sizes, int n_in,
                              void* d_out, int out_size, void* d_ws, size_t ws_size,
                              hipStream_t stream) {
    const float* obj_enc = (const float*)d_in[0];
    const int*   x       = (const int*)d_in[1];
    const float* qmm     = (const float*)d_in[2];
    const float* qlm     = (const float*)d_in[3];
    const float* qzm     = (const float*)d_in[4];
    const float* qmo     = (const float*)d_in[5];
    const float* qlo     = (const float*)d_in[6];
    const float* qzo     = (const float*)d_in[7];
    const float* emd     = (const float*)d_in[8];
    const float* W_ih_m  = (const float*)d_in[9];
    const float* W_hh_m  = (const float*)d_in[10];
    const float* b_m     = (const float*)d_in[11];
    const float* W_ih_o  = (const float*)d_in[12];
    const float* W_hh_o  = (const float*)d_in[13];
    const float* b_o     = (const float*)d_in[14];
    const float* fc_m_W  = (const float*)d_in[15];
    const float* fc_m_b  = (const float*)d_in[16];
    const float* fc_o_W  = (const float*)d_in[17];
    const float* fc_o_b  = (const float*)d_in[18];
    float* out = (float*)d_out;

    char* base = (char*)d_ws;
    size_t off = 0;
    auto alloc = [&](size_t bytes) { char* r = base + off; off += (bytes + 255) & ~(size_t)255; return r; };
    float* mask     = (float*)alloc((size_t)Bz * NOBJz * 4);
    u16* meanim_bf  = (u16*)alloc((size_t)Bz * Dz * 2);
    u16* Whh_m_bf   = (u16*)alloc((size_t)4 * HMz * HMz * 2);
    u16* Whh_o_bf   = (u16*)alloc((size_t)4 * HOz * HOz * 2);
    u16* Winp_m_bf  = (u16*)alloc((size_t)4 * HMz * KXM * 2);
    u16* Winp_o_bf  = (u16*)alloc((size_t)4 * HOz * KXO * 2);
    u16* Wmean_m_bf = (u16*)alloc((size_t)4 * HMz * Dz * 2);
    u16* Wmean_o_bf = (u16*)alloc((size_t)4 * HOz * Dz * 2);
    u16* Wfc_m_bf   = (u16*)alloc((size_t)1024 * HMz * 2);
    u16* Wfc_o_bf   = (u16*)alloc((size_t)1024 * HOz * 2);
    float* b_m_p    = (float*)alloc((size_t)4 * HMz * 4);
    float* b_o_p    = (float*)alloc((size_t)4 * HOz * 4);
    u16* Xin_m      = (u16*)alloc((size_t)Tz * Bz * KXM * 2);
    u16* Xin_o      = (u16*)alloc((size_t)Tz * Bz * KXO * 2);
    u16* const_m_bf = (u16*)alloc((size_t)Bz * 4 * HMz * 2);
    u16* const_o_bf = (u16*)alloc((size_t)Bz * 4 * HOz * 2);
    u16* Ginp_m_bf  = (u16*)alloc((size_t)Tz * Bz * 4 * HMz * 2);   // aliased by outs after loop
    u16* Ginp_o_bf  = (u16*)alloc((size_t)Tz * Bz * 4 * HOz * 2);
    float* c_m      = (float*)alloc((size_t)Bz * HMz * 4);
    float* c_o      = (float*)alloc((size_t)Bz * HOz * 4);
    u16* H_m        = (u16*)alloc((size_t)Tz * Bz * HMz * 2);
    u16* H_o        = (u16*)alloc((size_t)Tz * Bz * HOz * 2);
    float* outs_m = (float*)Ginp_m_bf;                              // 2 x 41.9MB inside 83.9MB
    float* outs_o = outs_m + (size_t)Tz * Bz * 1024;

    const int TB = Tz * Bz;

    obj_mask_kernel<<<Bz * NOBJz, 64, 0, stream>>>(obj_enc, mask);
    meanim_kernel<<<(Bz * Dz + 255) / 256, 256, 0, stream>>>(obj_enc, mask, meanim_bf);
    assemble_Xm<<<(TB * KXM + 255) / 256, 256, 0, stream>>>(Xin_m, qzm, x, emd);
    assemble_Xo<<<(TB * KXO + 255) / 256, 256, 0, stream>>>(Xin_o, qzm, qzo, x, emd);

    // weight conversions: LSTM weights get the gate-interleaved row permutation
    convert_pad<<<(4 * HMz * HMz + 255) / 256, 256, 0, stream>>>(Whh_m_bf, W_hh_m, 4 * HMz, HMz, HMz, 0, HMz, HMz);
    convert_pad<<<(4 * HOz * HOz + 255) / 256, 256, 0, stream>>>(Whh_o_bf, W_hh_o, 4 * HOz, HOz, HOz, 0, HOz, HOz);
    convert_pad<<<(4 * HMz * KXM + 255) / 256, 256, 0, stream>>>(Winp_m_bf, W_ih_m, 4 * HMz, Ez + EMBz, 2860, 0, KXM, HMz);
    convert_pad<<<(4 * HOz * KXO + 255) / 256, 256, 0, stream>>>(Winp_o_bf, W_ih_o, 4 * HOz, 2 * Ez + EMBz, 3372, 0, KXO, HOz);
    convert_pad<<<(4 * HMz * Dz + 255) / 256, 256, 0, stream>>>(Wmean_m_bf, W_ih_m, 4 * HMz, Dz, 2860, Ez + EMBz, Dz, HMz);
    convert_pad<<<(4 * HOz * Dz + 255) / 256, 256, 0, stream>>>(Wmean_o_bf, W_ih_o, 4 * HOz, Dz, 3372, 2 * Ez + EMBz, Dz, HOz);
    convert_pad<<<(1024 * HMz + 255) / 256, 256, 0, stream>>>(Wfc_m_bf, fc_m_W, 1024, HMz, HMz, 0, HMz, 0);
    convert_pad<<<(1024 * HOz + 255) / 256, 256, 0, stream>>>(Wfc_o_bf, fc_o_W, 1024, HOz, HOz, 0, HOz, 0);
    bias_perm<<<(4 * HMz + 255) / 256, 256, 0, stream>>>(b_m_p, b_m, HMz);
    bias_perm<<<(4 * HOz + 255) / 256, 256, 0, stream>>>(b_o_p, b_o, HOz);

    // const = bias + meanim projection (bf16, gate-interleaved cols)
    gemm128<<<dim3(4 * HMz / 128, Bz / 128), 256, 0, stream>>>(
        meanim_bf, Dz, Wmean_m_bf, Dz, const_m_bf, 4 * HMz, Dz, b_m_p, nullptr, 0u, 1);
    gemm128<<<dim3(4 * HOz / 128, Bz / 128), 256, 0, stream>>>(
        meanim_bf, Dz, Wmean_o_bf, Dz, const_o_bf, 4 * HOz, Dz, b_o_p, nullptr, 0u, 1);

    // Ginp = Xin @ Winp^T + const  (all T at once; addR row = global row & 511 = b)
    gemm128<<<dim3(4 * HMz / 128, TB / 128), 256, 0, stream>>>(
        Xin_m, KXM, Winp_m_bf, KXM, Ginp_m_bf, 4 * HMz, KXM, nullptr, const_m_bf, (unsigned)(Bz - 1), 1);
    gemm128<<<dim3(4 * HOz / 128, TB / 128), 256, 0, stream>>>(
        Xin_o, KXO, Winp_o_bf, KXO, Ginp_o_bf, 4 * HOz, KXO, nullptr, const_o_bf, (unsigned)(Bz - 1), 1);

    // t = 0: gates are Ginp only
    cell0<<<(Bz * (HMz + HOz) + 255) / 256, 256, 0, stream>>>(
        Ginp_m_bf, c_m, H_m, Ginp_o_bf, c_o, H_o);

    // t = 1..19: one fused GEMM+cell launch per step (mask: 128 blocks, obj: 32 blocks)
    for (int t = 1; t < Tz; ++t) {
        step_fused<<<160, 256, 0, stream>>>(
            H_m + (size_t)(t - 1) * Bz * HMz, Whh_m_bf, Ginp_m_bf + (size_t)t * Bz * 4 * HMz,
            c_m, H_m + (size_t)t * Bz * HMz,
            H_o + (size_t)(t - 1) * Bz * HOz, Whh_o_bf, Ginp_o_bf + (size_t)t * Bz * 4 * HOz,
            c_o, H_o + (size_t)t * Bz * HOz);
    }

    // FC heads over all (t,b) rows (normal column order, fp32 out)
    gemm128<<<dim3(1024 / 128, TB / 128), 256, 0, stream>>>(
        H_m, HMz, Wfc_m_bf, HMz, outs_m, 1024, HMz, fc_m_b, nullptr, 0u, 0);
    gemm128<<<dim3(1024 / 128, TB / 128), 256, 0, stream>>>(
        H_o, HOz, Wfc_o_bf, HOz, outs_o, 1024, HOz, fc_o_b, nullptr, 0u, 0);

    kl_kernel<<<Bz, 256, 0, stream>>>(outs_m, outs_o, qmm, qlm, qmo, qlo, x, out);
}